// Round 1
// baseline (116.030 us; speedup 1.0000x reference)
//
#include <hip/hip_runtime.h>
#include <cstdint>
#include <cstddef>

// Problem constants (fixed by setup_inputs)
#define ZSEQ 8
#define NSEQ 2048
#define NH 4
#define DH 128
#define QKV_STRIDE (NH * 3 * DH) /* 1536 floats per token row */
#define OUT_STRIDE (NH * DH)     /* 512 floats per token row */
#define ALPHA 0.08838834764831843f

typedef _Float16 h8 __attribute__((ext_vector_type(8)));
typedef _Float16 h4 __attribute__((ext_vector_type(4)));
typedef float fx16 __attribute__((ext_vector_type(16)));
typedef unsigned short u16t;

__device__ __forceinline__ h8 cvt8(float4 a, float4 b) {
  h8 r;
  r[0] = (_Float16)a.x; r[1] = (_Float16)a.y; r[2] = (_Float16)a.z; r[3] = (_Float16)a.w;
  r[4] = (_Float16)b.x; r[5] = (_Float16)b.y; r[6] = (_Float16)b.z; r[7] = (_Float16)b.w;
  return r;
}

// ---------------------------------------------------------------------------
// Prep: qkv f32 -> K16 [z][h][n][d] f16  and  Vt [z][h][d][n] f16 (transposed)
// 1024 blocks x 256 threads; each block handles one (z,h) x 64 rows.
// ---------------------------------------------------------------------------
__global__ __launch_bounds__(256) void prep_kernel(const float* __restrict__ qkv,
                                                   const int* __restrict__ seq_offsets,
                                                   u16t* __restrict__ k16,
                                                   u16t* __restrict__ vt) {
  __shared__ u16t Vl[64 * 136];  // padded rows (136 elems = 272B) to spread bank access
  const int t = threadIdx.x;
  const int b = blockIdx.x;
  const int z = b >> 7;          // 128 blocks per z (4 heads * 32 row-tiles)
  const int h = (b >> 5) & 3;
  const int nb = b & 31;
  const int n0 = nb * 64;
  const int start = seq_offsets[z];
  const int zh = z * NH + h;

#pragma unroll
  for (int i = 0; i < 2; ++i) {
    const int r = i * 32 + (t >> 3);
    const int c16 = (t & 7) * 16;
    const float* src = qkv + (size_t)(start + n0 + r) * QKV_STRIDE + h * (3 * DH);
    // ---- K ----
    float4 a0 = *(const float4*)(src + DH + c16);
    float4 a1 = *(const float4*)(src + DH + c16 + 4);
    float4 a2 = *(const float4*)(src + DH + c16 + 8);
    float4 a3 = *(const float4*)(src + DH + c16 + 12);
    u16t* kd = k16 + ((size_t)zh * NSEQ + n0 + r) * DH + c16;
    *(h8*)(kd) = cvt8(a0, a1);
    *(h8*)(kd + 8) = cvt8(a2, a3);
    // ---- V -> LDS (row-major, padded) ----
    float4 v0 = *(const float4*)(src + 2 * DH + c16);
    float4 v1 = *(const float4*)(src + 2 * DH + c16 + 4);
    float4 v2 = *(const float4*)(src + 2 * DH + c16 + 8);
    float4 v3 = *(const float4*)(src + 2 * DH + c16 + 12);
    *(h8*)((char*)Vl + r * 272 + c16 * 2) = cvt8(v0, v1);
    *(h8*)((char*)Vl + r * 272 + c16 * 2 + 16) = cvt8(v2, v3);
  }
  __syncthreads();
  // transpose out: Vt[d][n]
#pragma unroll
  for (int j = 0; j < 2; ++j) {
    const int d = j * 64 + (t >> 2);
    const int n16 = (t & 3) * 16;
    h8 o0, o1;
#pragma unroll
    for (int k2 = 0; k2 < 8; ++k2) {
      o0[k2] = *(const _Float16*)((const char*)Vl + (n16 + k2) * 272 + d * 2);
      o1[k2] = *(const _Float16*)((const char*)Vl + (n16 + 8 + k2) * 272 + d * 2);
    }
    u16t* dst = vt + ((size_t)zh * DH + d) * NSEQ + n0 + n16;
    *(h8*)dst = o0;
    *(h8*)(dst + 8) = o1;
  }
}

// ---------------------------------------------------------------------------
// Attention. 512 blocks (z,h,mt), 256 threads = 4 waves, BM=128 (32 rows/wave),
// KV tile = 64. MFMA 32x32x16 f16. S does a swizzled per-wave LDS round trip.
// FROM_QKV=1: fallback when d_ws too small (stages K/V from f32 qkv,
// transposing V through an extra LDS buffer).
// ---------------------------------------------------------------------------
template <int FROM_QKV>
__global__ __launch_bounds__(256) void attn_kernel(const float* __restrict__ qkv,
                                                   const int* __restrict__ seq_offsets,
                                                   const u16t* __restrict__ k16,
                                                   const u16t* __restrict__ vt,
                                                   float* __restrict__ out) {
  __shared__ u16t Ks[64 * 128];       // K tile  [n][d], rows 256B, XOR swizzle (n&7)<<4
  __shared__ u16t Vs[128 * 64];       // V tile  [d][n], rows 128B, XOR swizzle (d&7)<<4
  __shared__ u16t Ss[4 * 32 * 64];    // per-wave silu(S) [m][n], rows 128B, swizzled
  __shared__ u16t Vl[FROM_QKV ? 64 * 136 : 2];  // fallback transpose buffer

  const int t = threadIdx.x;
  const int lane = t & 63;
  const int w = t >> 6;
  const int l31 = lane & 31;
  const int lh = lane >> 5;  // 0/1

  const int g = blockIdx.x;
  const int z = g >> 6;
  const int h = (g >> 4) & 3;
  const int mtr = g & 15;
  // pair heavy tile with light tile on the same CU (blocks g and g+256)
  const int mt = (z >= 4) ? (15 - mtr) : mtr;
  const int m0 = mt * 128;
  const int start = seq_offsets[z];
  const int zh = z * NH + h;
  const int wm0 = m0 + w * 32;

  // ---- Q fragments in registers, pre-scaled by ALPHA ----
  h8 qf[8];
  {
    const float* qrow = qkv + (size_t)(start + wm0 + l31) * QKV_STRIDE + h * (3 * DH);
#pragma unroll
    for (int ks = 0; ks < 8; ++ks) {
      const int d0 = ks * 16 + lh * 8;
      float4 a = *(const float4*)(qrow + d0);
      float4 b = *(const float4*)(qrow + d0 + 4);
      a.x *= ALPHA; a.y *= ALPHA; a.z *= ALPHA; a.w *= ALPHA;
      b.x *= ALPHA; b.y *= ALPHA; b.z *= ALPHA; b.w *= ALPHA;
      qf[ks] = cvt8(a, b);
    }
  }

  fx16 oacc[4];
#pragma unroll
  for (int db = 0; db < 4; ++db)
#pragma unroll
    for (int i = 0; i < 16; ++i) oacc[db][i] = 0.0f;

  char* const ssb = (char*)Ss + w * 4096;
  const int ktmax = 2 * mt + 1;

  for (int kt = 0; kt <= ktmax; ++kt) {
    const int n0 = kt * 64;
    __syncthreads();  // previous tile's LDS reads done
    if (FROM_QKV) {
      // K tile from f32 qkv
#pragma unroll
      for (int i = 0; i < 8; ++i) {
        const int f = i * 256 + t;
        const int r = f >> 5, c4 = f & 31;
        const float* src = qkv + (size_t)(start + n0 + r) * QKV_STRIDE + h * (3 * DH) + DH + c4 * 4;
        float4 a = *(const float4*)src;
        h4 p; p[0] = (_Float16)a.x; p[1] = (_Float16)a.y; p[2] = (_Float16)a.z; p[3] = (_Float16)a.w;
        *(h4*)((char*)Ks + r * 256 + ((c4 * 8) ^ ((r & 7) << 4))) = p;
      }
      // V tile rows -> Vl (padded)
#pragma unroll
      for (int i = 0; i < 8; ++i) {
        const int f = i * 256 + t;
        const int r = f >> 5, c4 = f & 31;
        const float* src = qkv + (size_t)(start + n0 + r) * QKV_STRIDE + h * (3 * DH) + 2 * DH + c4 * 4;
        float4 a = *(const float4*)src;
        h4 p; p[0] = (_Float16)a.x; p[1] = (_Float16)a.y; p[2] = (_Float16)a.z; p[3] = (_Float16)a.w;
        *(h4*)((char*)Vl + r * 272 + c4 * 8) = p;
      }
      __syncthreads();
      // transpose Vl -> Vs
#pragma unroll
      for (int j = 0; j < 2; ++j) {
        const int d = j * 64 + (t >> 2);
        const int n16 = (t & 3) * 16;
        h8 o0, o1;
#pragma unroll
        for (int k2 = 0; k2 < 8; ++k2) {
          o0[k2] = *(const _Float16*)((const char*)Vl + (n16 + k2) * 272 + d * 2);
          o1[k2] = *(const _Float16*)((const char*)Vl + (n16 + 8 + k2) * 272 + d * 2);
        }
        *(h8*)((char*)Vs + d * 128 + ((n16 * 2) ^ ((d & 7) << 4))) = o0;
        *(h8*)((char*)Vs + d * 128 + (((n16 + 8) * 2) ^ ((d & 7) << 4))) = o1;
      }
    } else {
      // K tile from pre-cast f16
#pragma unroll
      for (int i = 0; i < 4; ++i) {
        const int f = i * 256 + t;
        const int r = f >> 4, cb = f & 15;
        h8 v = *(const h8*)(k16 + ((size_t)zh * NSEQ + n0 + r) * DH + cb * 8);
        *(h8*)((char*)Ks + r * 256 + ((cb * 16) ^ ((r & 7) << 4))) = v;
      }
      // V tile (already transposed in global)
#pragma unroll
      for (int i = 0; i < 4; ++i) {
        const int f = i * 256 + t;
        const int d = f >> 3, cb = f & 7;
        h8 v = *(const h8*)(vt + ((size_t)zh * DH + d) * NSEQ + n0 + cb * 8);
        *(h8*)((char*)Vs + d * 128 + ((cb * 16) ^ ((d & 7) << 4))) = v;
      }
    }
    __syncthreads();  // tiles ready

    if (n0 > wm0 + 31) continue;  // wave-uniform: fully masked tile for this wave

    // ---- S = Q K^T (pre-scaled) ----
    fx16 s0, s1;
#pragma unroll
    for (int i = 0; i < 16; ++i) { s0[i] = 0.0f; s1[i] = 0.0f; }
#pragma unroll
    for (int ks = 0; ks < 8; ++ks) {
      const int cb = 32 * ks + 16 * lh;
      const int r0 = l31, r1 = 32 + l31;
      h8 b0 = *(const h8*)((const char*)Ks + r0 * 256 + (cb ^ ((r0 & 7) << 4)));
      h8 b1 = *(const h8*)((const char*)Ks + r1 * 256 + (cb ^ ((r1 & 7) << 4)));
      s0 = __builtin_amdgcn_mfma_f32_32x32x16_f16(qf[ks], b0, s0, 0, 0, 0);
      s1 = __builtin_amdgcn_mfma_f32_32x32x16_f16(qf[ks], b1, s1, 0, 0, 0);
    }

    // ---- silu + causal mask, write to per-wave Ss (f16) ----
    const bool needmask = (n0 + 63 > wm0);
#pragma unroll
    for (int nb = 0; nb < 2; ++nb) {
      const fx16 s = nb ? s1 : s0;
      const int n_l = nb * 32 + l31;
#pragma unroll
      for (int i = 0; i < 16; ++i) {
        const int mloc = (i & 3) + 8 * (i >> 2) + 4 * lh;
        const float sv = s[i];
        const float e = __expf(-sv);
        float sil = sv * __builtin_amdgcn_rcpf((1.0f + e) * 2048.0f);
        if (needmask && (n0 + n_l > wm0 + mloc)) sil = 0.0f;
        *(_Float16*)(ssb + mloc * 128 + ((n_l * 2) ^ ((mloc & 7) << 4))) = (_Float16)sil;
      }
    }

    // ---- O += silu(S) * V ----  (same-wave LDS RAW: compiler inserts lgkmcnt)
#pragma unroll
    for (int ks = 0; ks < 4; ++ks) {
      const int cb = 32 * ks + 16 * lh;
      h8 pa = *(const h8*)(ssb + l31 * 128 + (cb ^ ((l31 & 7) << 4)));
#pragma unroll
      for (int db = 0; db < 4; ++db) {
        const int rr = db * 32 + l31;
        h8 bv = *(const h8*)((const char*)Vs + rr * 128 + (cb ^ ((rr & 7) << 4)));
        oacc[db] = __builtin_amdgcn_mfma_f32_32x32x16_f16(pa, bv, oacc[db], 0, 0, 0);
      }
    }
  }

  // ---- epilogue: write f32 output ----
#pragma unroll
  for (int db = 0; db < 4; ++db) {
    const int d = db * 32 + l31;
#pragma unroll
    for (int i = 0; i < 16; ++i) {
      const int mloc = (i & 3) + 8 * (i >> 2) + 4 * lh;
      const int row = wm0 + mloc;
      out[(size_t)(start + row) * OUT_STRIDE + h * DH + d] = oacc[db][i];
    }
  }
}

// ---------------------------------------------------------------------------
extern "C" void kernel_launch(void* const* d_in, const int* in_sizes, int n_in,
                              void* d_out, int out_size, void* d_ws, size_t ws_size,
                              hipStream_t stream) {
  (void)in_sizes; (void)n_in; (void)out_size;
  const float* qkv = (const float*)d_in[0];
  const int* seq_offsets = (const int*)d_in[1];
  // d_in[2..4] (timestamps, ts_weights, pos_weights) unused by the reference.
  float* out = (float*)d_out;

  const size_t half_elems = (size_t)ZSEQ * NH * NSEQ * DH;  // 8,388,608
  const size_t need = 2 * half_elems * sizeof(u16t);        // 32 MiB

  if (ws_size >= need) {
    u16t* k16 = (u16t*)d_ws;
    u16t* vt = k16 + half_elems;
    prep_kernel<<<ZSEQ * NH * (NSEQ / 64), 256, 0, stream>>>(qkv, seq_offsets, k16, vt);
    attn_kernel<0><<<ZSEQ * NH * (NSEQ / 128), 256, 0, stream>>>(qkv, seq_offsets, k16, vt, out);
  } else {
    attn_kernel<1><<<ZSEQ * NH * (NSEQ / 128), 256, 0, stream>>>(qkv, seq_offsets, nullptr, nullptr, out);
  }
}

// Round 4
// 95.345 us; speedup vs baseline: 1.2170x; 1.2170x over previous
//
#include <hip/hip_runtime.h>
#include <cstdint>
#include <cstddef>

// Problem constants (fixed by setup_inputs)
#define ZSEQ 8
#define NSEQ 2048
#define NH 4
#define DH 128
#define QKV_STRIDE (NH * 3 * DH) /* 1536 floats per token row */
#define OUT_STRIDE (NH * DH)     /* 512 floats per token row */
#define ALPHA 0.08838834764831843f
#define TILE_B 16384             /* bytes per 64-row K tile / per V tile */

typedef _Float16 h8 __attribute__((ext_vector_type(8)));
typedef __fp16 fp16x2 __attribute__((ext_vector_type(2)));
typedef float fx16 __attribute__((ext_vector_type(16)));
typedef unsigned int ui4v __attribute__((ext_vector_type(4)));
typedef unsigned short u16t;

// global_load_lds: per-lane global src, wave-uniform LDS base (HW adds lane*16)
#define GLDS(gp, lp)                                                        \
  __builtin_amdgcn_global_load_lds(                                         \
      (__attribute__((address_space(1))) void*)(gp),                        \
      (__attribute__((address_space(3))) void*)(lp), 16, 0, 0)

__device__ __forceinline__ h8 cvt8(float4 a, float4 b) {
  h8 r;
  r[0] = (_Float16)a.x; r[1] = (_Float16)a.y; r[2] = (_Float16)a.z; r[3] = (_Float16)a.w;
  r[4] = (_Float16)b.x; r[5] = (_Float16)b.y; r[6] = (_Float16)b.z; r[7] = (_Float16)b.w;
  return r;
}

__device__ __forceinline__ unsigned pku(float a, float b) {
  union { fp16x2 h; unsigned u; } c;
  c.h = __builtin_amdgcn_cvt_pkrtz(a, b);
  return c.u;
}

// ---------------------------------------------------------------------------
// Prep: qkv f32 -> pre-swizzled f16 tiles in d_ws.
//   K tiles: [zh][nt][64 rows x 256B], byte col c stored at c ^ ((row&7)<<4)
//   V tiles: [zh][nt][128 d-rows x 128B], col c stored at c ^ ((d&7)<<4)
//   V tile COLUMN ORDER is bit2<->bit3 swapped in n (pi(c) = swap bits 2,3):
//   column c holds V row n0 + pi(c). This matches the natural per-lane order
//   of S^T fragments after swapped-QK^T MFMA, so PV needs NO cross-lane ops.
// ---------------------------------------------------------------------------
__global__ __launch_bounds__(256) void prep_kernel(const float* __restrict__ qkv,
                                                   const int* __restrict__ seq_offsets,
                                                   char* __restrict__ k16,
                                                   char* __restrict__ vt) {
  __shared__ u16t Vl[64 * 136];  // padded transpose staging
  const int t = threadIdx.x;
  const int b = blockIdx.x;
  const int z = b >> 7;
  const int h = (b >> 5) & 3;
  const int nb = b & 31;
  const int n0 = nb * 64;
  const int start = seq_offsets[z];
  const int zh = z * NH + h;
  const size_t tb = (size_t)(zh * 32 + nb) * TILE_B;

#pragma unroll
  for (int i = 0; i < 2; ++i) {
    const int r = i * 32 + (t >> 3);
    const int c16 = (t & 7) * 16;  // element col
    const int cb = c16 * 2;        // byte col
    const float* src = qkv + (size_t)(start + n0 + r) * QKV_STRIDE + h * (3 * DH);
    // ---- K (swizzled) ----
    float4 a0 = *(const float4*)(src + DH + c16);
    float4 a1 = *(const float4*)(src + DH + c16 + 4);
    float4 a2 = *(const float4*)(src + DH + c16 + 8);
    float4 a3 = *(const float4*)(src + DH + c16 + 12);
    char* kd = k16 + tb + r * 256;
    *(h8*)(kd + (cb ^ ((r & 7) << 4))) = cvt8(a0, a1);
    *(h8*)(kd + ((cb + 16) ^ ((r & 7) << 4))) = cvt8(a2, a3);
    // ---- V -> LDS (row-major, padded) ----
    float4 v0 = *(const float4*)(src + 2 * DH + c16);
    float4 v1 = *(const float4*)(src + 2 * DH + c16 + 4);
    float4 v2 = *(const float4*)(src + 2 * DH + c16 + 8);
    float4 v3 = *(const float4*)(src + 2 * DH + c16 + 12);
    *(h8*)((char*)Vl + r * 272 + cb) = cvt8(v0, v1);
    *(h8*)((char*)Vl + r * 272 + cb + 16) = cvt8(v2, v3);
  }
  __syncthreads();
  // transpose out: V tile rows = d, cols = n with pi (bits 2,3 of n swapped)
#pragma unroll
  for (int j = 0; j < 2; ++j) {
    const int d = j * 64 + (t >> 2);
    const int n16 = (t & 3) * 16;
    const int cn = n16 * 2;  // byte col of this 16-col group
    h8 o0, o1;
    // column group c = 0..7 holds rows {0,1,2,3, 8,9,10,11} + n16
    // column group c = 8..15 holds rows {4,5,6,7, 12,13,14,15} + n16
#pragma unroll
    for (int k2 = 0; k2 < 8; ++k2) {
      const int r0 = (k2 & 3) + 8 * (k2 >> 2);
      o0[k2] = *(const _Float16*)((const char*)Vl + (n16 + r0) * 272 + d * 2);
      o1[k2] = *(const _Float16*)((const char*)Vl + (n16 + 4 + r0) * 272 + d * 2);
    }
    char* vd = vt + tb + d * 128;
    *(h8*)(vd + (cn ^ ((d & 7) << 4))) = o0;
    *(h8*)(vd + ((cn + 16) ^ ((d & 7) << 4))) = o1;
  }
}

// silu + causal mask on one S^T accumulator (in place).
// s element i holds S^T at n = n0 + nbase + (i&3) + 8*(i>>2) + 4*lh, col m=mrow.
__device__ __forceinline__ void silu_mask(fx16& s, int nbase, bool needmask, int n0,
                                          int mrow, int lh) {
#pragma unroll
  for (int i = 0; i < 16; ++i) {
    const float sv = s[i];
    float sil = sv * __builtin_amdgcn_rcpf((1.0f + __expf(-sv)) * 2048.0f);
    if (needmask && (n0 + nbase + (i & 3) + 8 * (i >> 2) + 4 * lh > mrow)) sil = 0.0f;
    s[i] = sil;
  }
}

// pack 8 consecutive s elements (b = 0 or 8) into an f16 A-fragment.
// Fragment element j (= k-offset) gets s[b+j]; combined with the pi-permuted
// V column order this makes PV exact. No cross-lane ops.
__device__ __forceinline__ h8 pack8(const fx16& s, int b) {
  union { ui4v u; h8 h; } cv;
  cv.u = (ui4v){pku(s[b + 0], s[b + 1]), pku(s[b + 2], s[b + 3]),
                pku(s[b + 4], s[b + 5]), pku(s[b + 6], s[b + 7])};
  return cv.h;
}

// ---------------------------------------------------------------------------
// Attention: 512 blocks (z,h,mt), 256 threads = 4 waves, BM=128 (32 rows/wave),
// KV tile 64. Swapped QK^T -> in-register silu -> packed PV A-frags (no Ss).
// K/V double-buffered in LDS via global_load_lds; loads for tile k+1 issued
// before compute of tile k; ONE __syncthreads per tile.
// ---------------------------------------------------------------------------
__global__ __launch_bounds__(256, 2) void attn_kernel(const float* __restrict__ qkv,
                                                      const int* __restrict__ seq_offsets,
                                                      const char* __restrict__ k16,
                                                      const char* __restrict__ vt,
                                                      float* __restrict__ out) {
  __shared__ u16t Ks[2][64 * 128];   // 16KB per buf
  __shared__ u16t Vs[2][128 * 64];   // 16KB per buf

  const int t = threadIdx.x;
  const int lane = t & 63;
  const int w = t >> 6;
  const int l31 = lane & 31;
  const int lh = lane >> 5;

  const int g = blockIdx.x;
  const int z = g >> 6;
  const int h = (g >> 4) & 3;
  const int mtr = g & 15;
  const int mt = (z >= 4) ? (15 - mtr) : mtr;  // pair heavy+light on same CU
  const int m0 = mt * 128;
  const int start = seq_offsets[z];
  const int zh = z * NH + h;
  const int wm0 = m0 + w * 32;
  const int mrow = wm0 + l31;  // this lane's output row (seq-local)

  // ---- Q fragments (B-operand: col=m=l31, k=d), pre-scaled by ALPHA ----
  h8 qf[8];
  {
    const float* qrow = qkv + (size_t)(start + mrow) * QKV_STRIDE + h * (3 * DH);
#pragma unroll
    for (int ks = 0; ks < 8; ++ks) {
      const int d0 = ks * 16 + lh * 8;
      float4 a = *(const float4*)(qrow + d0);
      float4 b = *(const float4*)(qrow + d0 + 4);
      a.x *= ALPHA; a.y *= ALPHA; a.z *= ALPHA; a.w *= ALPHA;
      b.x *= ALPHA; b.y *= ALPHA; b.z *= ALPHA; b.w *= ALPHA;
      qf[ks] = cvt8(a, b);
    }
  }

  fx16 oacc[4];
#pragma unroll
  for (int db = 0; db < 4; ++db)
#pragma unroll
    for (int i = 0; i < 16; ++i) oacc[db][i] = 0.0f;

  const size_t tbase = (size_t)(zh * 32) * TILE_B;

  // stage tile kt2 into buffer buf (8 global_load_lds per wave)
  auto stage = [&](int buf, int kt2) {
    const char* kg = k16 + tbase + (size_t)kt2 * TILE_B + w * 4096 + lane * 16;
    const char* vg = vt + tbase + (size_t)kt2 * TILE_B + w * 4096 + lane * 16;
    u16t* kl = &Ks[buf][w * 2048];  // wave-uniform LDS base (u16 units)
    u16t* vl = &Vs[buf][w * 2048];
#pragma unroll
    for (int i = 0; i < 4; ++i) {
      GLDS(kg + i * 1024, kl + i * 512);
      GLDS(vg + i * 1024, vl + i * 512);
    }
  };

  const int ktmax = 2 * mt + 1;
  int buf = 0;
  stage(0, 0);
  __syncthreads();  // tile 0 landed (prologue)

  for (int kt = 0; kt <= ktmax; ++kt) {
    if (kt < ktmax) stage(buf ^ 1, kt + 1);  // issue next-tile loads early
    const int n0 = kt * 64;
    if (n0 <= wm0 + 31) {
      const char* kb = (const char*)&Ks[buf][0];
      const char* vb = (const char*)&Vs[buf][0];
      // ---- S^T = K Q^T (A=K rows n, B=Q cols m) ----
      fx16 s0, s1;
#pragma unroll
      for (int i = 0; i < 16; ++i) { s0[i] = 0.0f; s1[i] = 0.0f; }
#pragma unroll
      for (int ks = 0; ks < 8; ++ks) {
        const int cb = 32 * ks + 16 * lh;
        const int sw = (l31 & 7) << 4;
        h8 a0 = *(const h8*)(kb + l31 * 256 + (cb ^ sw));
        h8 a1 = *(const h8*)(kb + (32 + l31) * 256 + (cb ^ sw));
        s0 = __builtin_amdgcn_mfma_f32_32x32x16_f16(a0, qf[ks], s0, 0, 0, 0);
        s1 = __builtin_amdgcn_mfma_f32_32x32x16_f16(a1, qf[ks], s1, 0, 0, 0);
      }
      // ---- silu + mask (in-register), pack to PV A-fragments ----
      const bool needmask = (n0 + 63 > wm0);
      silu_mask(s0, 0, needmask, n0, mrow, lh);
      silu_mask(s1, 32, needmask, n0, mrow, lh);
      h8 pa[4];
      pa[0] = pack8(s0, 0);
      pa[1] = pack8(s0, 8);
      pa[2] = pack8(s1, 0);
      pa[3] = pack8(s1, 8);
      // ---- O += P V ----  (V columns are pi-permuted to match pa order)
#pragma unroll
      for (int ks = 0; ks < 4; ++ks) {
        const int cb = 32 * ks + 16 * lh;
#pragma unroll
        for (int db = 0; db < 4; ++db) {
          const int rr = db * 32 + l31;
          h8 bv = *(const h8*)(vb + rr * 128 + (cb ^ ((rr & 7) << 4)));
          oacc[db] = __builtin_amdgcn_mfma_f32_32x32x16_f16(pa[ks], bv, oacc[db], 0, 0, 0);
        }
      }
    }
    __syncthreads();  // drain next-tile loads + gate buffer reuse
    buf ^= 1;
  }

  // ---- epilogue: f32 output ----
#pragma unroll
  for (int db = 0; db < 4; ++db) {
    const int d = db * 32 + l31;
#pragma unroll
    for (int i = 0; i < 16; ++i) {
      const int m = wm0 + (i & 3) + 8 * (i >> 2) + 4 * lh;
      out[(size_t)(start + m) * OUT_STRIDE + h * DH + d] = oacc[db][i];
    }
  }
}

// ---------------------------------------------------------------------------
// Never-expected fallback (ws too small): naive per-(token,head) block.
// ---------------------------------------------------------------------------
__global__ __launch_bounds__(128) void fallback_kernel(const float* __restrict__ qkv,
                                                       const int* __restrict__ seq_offsets,
                                                       float* __restrict__ out) {
  const int token = blockIdx.x;
  const int h = blockIdx.y;
  const int z = token >> 11;
  const int m = token & 2047;
  const int start = seq_offsets[z];
  const int t = threadIdx.x;  // = d
  const float qd = qkv[(size_t)(start + m) * QKV_STRIDE + h * (3 * DH) + t] * ALPHA;
  __shared__ float red[2];
  float acc = 0.0f;
  for (int n = 0; n <= m; ++n) {
    const float kd = qkv[(size_t)(start + n) * QKV_STRIDE + h * (3 * DH) + DH + t];
    float part = qd * kd;
#pragma unroll
    for (int o = 32; o; o >>= 1) part += __shfl_down(part, o);
    if ((t & 63) == 0) red[t >> 6] = part;
    __syncthreads();
    const float s = red[0] + red[1];
    const float sil = s / ((1.0f + __expf(-s)) * 2048.0f);
    acc += sil * qkv[(size_t)(start + n) * QKV_STRIDE + h * (3 * DH) + 2 * DH + t];
    __syncthreads();
  }
  out[(size_t)(start + m) * OUT_STRIDE + h * DH + t] = acc;
}

// ---------------------------------------------------------------------------
extern "C" void kernel_launch(void* const* d_in, const int* in_sizes, int n_in,
                              void* d_out, int out_size, void* d_ws, size_t ws_size,
                              hipStream_t stream) {
  (void)in_sizes; (void)n_in; (void)out_size;
  const float* qkv = (const float*)d_in[0];
  const int* seq_offsets = (const int*)d_in[1];
  // d_in[2..4] (timestamps, ts_weights, pos_weights) unused by the reference.
  float* out = (float*)d_out;

  const size_t half = (size_t)ZSEQ * NH * 32 * TILE_B;  // 16 MiB (bytes)

  if (ws_size >= 2 * half) {
    char* k16 = (char*)d_ws;
    char* vt = k16 + half;
    prep_kernel<<<ZSEQ * NH * (NSEQ / 64), 256, 0, stream>>>(qkv, seq_offsets, k16, vt);
    attn_kernel<<<ZSEQ * NH * (NSEQ / 128), 256, 0, stream>>>(qkv, seq_offsets, k16, vt, out);
  } else {
    fallback_kernel<<<dim3(ZSEQ * NSEQ, NH), 128, 0, stream>>>(qkv, seq_offsets, out);
  }
}